// Round 2
// baseline (414.570 us; speedup 1.0000x reference)
//
#include <hip/hip_runtime.h>
#include <hip/hip_bf16.h>

typedef float f32x4 __attribute__((ext_vector_type(4)));
typedef __bf16 bf16x8 __attribute__((ext_vector_type(8)));
typedef unsigned short u16;
typedef unsigned short u16x4 __attribute__((ext_vector_type(4)));
typedef unsigned short u16x8 __attribute__((ext_vector_type(8)));

#define BM 128
#define BN 128
#define BK 32
#define NT 256

// round-to-nearest-even fp32 -> bf16 (unbiased; bias would accumulate across K)
__device__ __forceinline__ u16 f2bf(float f) {
  unsigned u = __builtin_bit_cast(unsigned, f);
  u += 0x7fffu + ((u >> 16) & 1u);
  return (u16)(u >> 16);
}

// Grouped GEMM: Out[m, n] = act( sum_k A[m,k] * B[e][n,k] + bias[e][n] )
// A is [T][K] (fp32 or bf16 raw-u16), B is [E][N][K] fp32, rows grouped by expert.
// 2-deep pipeline: LDS holds tile kt (double-buffered), registers hold tile kt+1.
template<bool A_BF16, bool DO_GELU, bool OUT_BF16>
__global__ __launch_bounds__(NT)
void ffn_gemm(const void* __restrict__ Ain, const float* __restrict__ Bw,
              const float* __restrict__ bias, void* __restrict__ Out,
              const int* __restrict__ counts, int E, int T, int N, int K,
              int gxl, int nwg)
{
  // bijective XCD-chunk swizzle (m204): each XCD owns a contiguous run of
  // flat block ids -> A-panel sharers (consecutive x) and w-panel sharers
  // (y-neighbors) co-locate in one XCD's L2.
  int flat = blockIdx.x;
  {
    int q = nwg >> 3, r = nwg & 7;
    int xcd = flat & 7, idx = flat >> 3;
    flat = (xcd < r ? xcd * (q + 1) : r * (q + 1) + (xcd - r) * q) + idx;
  }
  int mt = flat >> gxl;
  const int n0 = (flat & ((1 << gxl) - 1)) * BN;

  // (expert, row-tile) via prefix over runtime counts
  int row0 = 0, cnt = 0, e = 0;
  for (; e < E; ++e) {
    cnt = counts[e];
    int ntl = (cnt + BM - 1) / BM;
    if (mt < ntl) break;
    mt -= ntl; row0 += cnt;
  }
  if (e >= E) return;
  int valid = cnt - mt * BM; if (valid > BM) valid = BM;
  row0 += mt * BM;

  const float* Be = Bw + (long long)e * N * K;
  const float* be = bias + (long long)e * N;

  __shared__ u16 As[2][BM][BK];
  __shared__ u16 Bs[2][BN][BK];

  const int t = threadIdx.x;
  const int lane = t & 63;
  const int w = t >> 6, wr = w >> 1, wc = w & 1;  // 2x2 waves -> 64x64 each

  f32x4 acc[4][4];
#pragma unroll
  for (int i = 0; i < 4; ++i)
#pragma unroll
    for (int j = 0; j < 4; ++j) acc[i][j] = (f32x4){0.f, 0.f, 0.f, 0.f};

  const int NKT = K / BK;

  // hoisted per-thread global element offsets (K-invariant)
  long long offA[4];
  if constexpr (!A_BF16) {
#pragma unroll
    for (int i = 0; i < 4; ++i) {
      int c = i * NT + t;
      int row = c >> 3, col = (c & 7) << 2;
      int gr = row0 + row; if (gr > T - 1) gr = T - 1;
      offA[i] = (long long)gr * K + col;
    }
  } else {
#pragma unroll
    for (int i = 0; i < 2; ++i) {
      int c = i * NT + t;
      int row = c >> 2, col = (c & 3) << 3;
      int gr = row0 + row; if (gr > T - 1) gr = T - 1;
      offA[i] = (long long)gr * K + col;
    }
  }
  long long offB[4];
#pragma unroll
  for (int i = 0; i < 4; ++i) {
    int c = i * NT + t;
    int row = c >> 3, col = (c & 7) << 2;
    offB[i] = (long long)(n0 + row) * K + col;
  }

  float rA[16]; u16x8 rAu[2]; float rB[16];

  auto load_g = [&](int kt) {
    const int k0 = kt * BK;
    if constexpr (!A_BF16) {
      const float* Af = (const float*)Ain;
#pragma unroll
      for (int i = 0; i < 4; ++i) {
        f32x4 v = *(const f32x4*)(Af + offA[i] + k0);
        rA[i*4+0] = v[0]; rA[i*4+1] = v[1]; rA[i*4+2] = v[2]; rA[i*4+3] = v[3];
      }
    } else {
      const u16* Ab = (const u16*)Ain;
#pragma unroll
      for (int i = 0; i < 2; ++i)
        rAu[i] = *(const u16x8*)(Ab + offA[i] + k0);
    }
#pragma unroll
    for (int i = 0; i < 4; ++i) {
      f32x4 v = *(const f32x4*)(Be + offB[i] + k0);
      rB[i*4+0] = v[0]; rB[i*4+1] = v[1]; rB[i*4+2] = v[2]; rB[i*4+3] = v[3];
    }
  };

  // XOR-swizzle on 16B granules: physical granule = kg ^ ((row>>1)&3)
  auto store_tile = [&](int buf) {
    if constexpr (!A_BF16) {
#pragma unroll
      for (int i = 0; i < 4; ++i) {
        int c = i * NT + t;
        int row = c >> 3, col = (c & 7) << 2;
        int kg = (col >> 3) ^ ((row >> 1) & 3);
        int off = kg * 8 + ((col >> 2) & 1) * 4;
        u16x4 pk = { f2bf(rA[i*4+0]), f2bf(rA[i*4+1]), f2bf(rA[i*4+2]), f2bf(rA[i*4+3]) };
        *(u16x4*)&As[buf][row][off] = pk;
      }
    } else {
#pragma unroll
      for (int i = 0; i < 2; ++i) {
        int c = i * NT + t;
        int row = c >> 2, col = (c & 3) << 3;
        int kg = (col >> 3) ^ ((row >> 1) & 3);
        *(u16x8*)&As[buf][row][kg * 8] = rAu[i];
      }
    }
#pragma unroll
    for (int i = 0; i < 4; ++i) {
      int c = i * NT + t;
      int row = c >> 3, col = (c & 7) << 2;
      int kg = (col >> 3) ^ ((row >> 1) & 3);
      int off = kg * 8 + ((col >> 2) & 1) * 4;
      u16x4 pk = { f2bf(rB[i*4+0]), f2bf(rB[i*4+1]), f2bf(rB[i*4+2]), f2bf(rB[i*4+3]) };
      *(u16x4*)&Bs[buf][row][off] = pk;
    }
  };

  // prologue: LDS buf0 <- tile 0; regs <- tile 1
  load_g(0);
  store_tile(0);
  load_g(1);
  __syncthreads();

  for (int kt = 0; kt < NKT; ++kt) {
    const int cur = kt & 1;

    // fragments for tile kt from LDS
    bf16x8 af[4], bfr[4];
    const int rl = lane & 15;
    const int kg = (lane >> 4) ^ ((rl >> 1) & 3);
#pragma unroll
    for (int mf = 0; mf < 4; ++mf)
      af[mf] = __builtin_bit_cast(bf16x8, *(const u16x8*)&As[cur][wr*64 + mf*16 + rl][kg*8]);
#pragma unroll
    for (int nf = 0; nf < 4; ++nf)
      bfr[nf] = __builtin_bit_cast(bf16x8, *(const u16x8*)&Bs[cur][wc*64 + nf*16 + rl][kg*8]);

    // drain regs (tile kt+1, loaded one full iteration ago) into other buffer
    if (kt + 1 < NKT) store_tile(cur ^ 1);
    // issue loads for tile kt+2 (waited at iter kt+1's store)
    if (kt + 2 < NKT) load_g(kt + 2);

#pragma unroll
    for (int mf = 0; mf < 4; ++mf)
#pragma unroll
      for (int nf = 0; nf < 4; ++nf)
        acc[mf][nf] = __builtin_amdgcn_mfma_f32_16x16x32_bf16(af[mf], bfr[nf], acc[mf][nf], 0, 0, 0);

    if (kt + 1 < NKT) __syncthreads();
  }

  // epilogue: C/D layout col = lane&15, row = (lane>>4)*4 + r  [verified m89/m91]
  const int cl = lane & 15, rg = lane >> 4;
#pragma unroll
  for (int mf = 0; mf < 4; ++mf) {
#pragma unroll
    for (int nf = 0; nf < 4; ++nf) {
      int gcol = n0 + wc*64 + nf*16 + cl;
      float bv = be[gcol];
#pragma unroll
      for (int r = 0; r < 4; ++r) {
        int lrow = wr*64 + mf*16 + rg*4 + r;
        if (lrow < valid) {
          float v = acc[mf][nf][r] + bv;
          if constexpr (DO_GELU)
            v = 0.5f * v * (1.0f + erff(v * 0.70710678118654752f));
          long long idx = (long long)(row0 + lrow) * N + gcol;
          if constexpr (OUT_BF16) ((u16*)Out)[idx] = f2bf(v);
          else                    ((float*)Out)[idx] = v;
        }
      }
    }
  }
}

extern "C" void kernel_launch(void* const* d_in, const int* in_sizes, int n_in,
                              void* d_out, int out_size, void* d_ws, size_t ws_size,
                              hipStream_t stream) {
  const float* inp = (const float*)d_in[0];
  const float* w1  = (const float*)d_in[1];
  const float* b1  = (const float*)d_in[2];
  const float* w2  = (const float*)d_in[3];
  const float* b2  = (const float*)d_in[4];
  const int* cnts  = (const int*)d_in[5];

  const int E = in_sizes[5];
  const int H = in_sizes[2] / E;       // 4096
  const int D = in_sizes[4] / E;       // 1024
  const int T = in_sizes[0] / D;       // 8192

  u16* hbuf = (u16*)d_ws;              // T*H bf16 intermediate (64 MB)

  const int tiles = (T + BM - 1) / BM + E;  // upper bound on sum of per-expert row-tiles
  dim3 blk(NT);

  const int gx1 = H / BN, gxl1 = __builtin_ctz(gx1);
  const int nwg1 = gx1 * tiles;
  ffn_gemm<false, true, true><<<dim3(nwg1), blk, 0, stream>>>(
      (const void*)inp, w1, b1, (void*)hbuf, cnts, E, T, H, D, gxl1, nwg1);

  const int gx2 = D / BN, gxl2 = __builtin_ctz(gx2);
  const int nwg2 = gx2 * tiles;
  ffn_gemm<true, false, false><<<dim3(nwg2), blk, 0, stream>>>(
      (const void*)hbuf, w2, b2, d_out, cnts, E, T, D, H, gxl2, nwg2);
}

// Round 3
// 328.776 us; speedup vs baseline: 1.2609x; 1.2609x over previous
//
#include <hip/hip_runtime.h>
#include <hip/hip_bf16.h>

typedef float f32x4 __attribute__((ext_vector_type(4)));
typedef __bf16 bf16x8 __attribute__((ext_vector_type(8)));
typedef unsigned short u16;
typedef unsigned short u16x4 __attribute__((ext_vector_type(4)));
typedef unsigned short u16x8 __attribute__((ext_vector_type(8)));

#define BM 128
#define BN 128
#define BK 32
#define NT 256

// fp32 -> bf16 via native hardware cvt (RNE). Plain cast lets clang emit
// v_cvt_pk_bf16_f32 (2 elem/inst) -- the integer-RNE version cost ~4 VALU/elem
// and capped MfmaUtil at ~11% (round-1 rocprof).
__device__ __forceinline__ u16 f2bf(float f) {
  __bf16 h = (__bf16)f;
  return __builtin_bit_cast(u16, h);
}

// Grouped GEMM: Out[m, n] = act( sum_k A[m,k] * B[e][n,k] + bias[e][n] )
// A is [T][K] (fp32 or bf16 raw-u16), B is [E][N][K] fp32, rows grouped by expert.
// 2-deep pipeline: LDS holds tile kt (double-buffered), registers hold tile kt+1.
// Grid: x = column tiles (fastest; keeps one expert's w-panel L3-temporal),
//       y = (expert,row-tile) via prefix over runtime counts. NO XCD swizzle:
//       round-2 showed chunked swizzle spreads 8 expert regions concurrently
//       -> w1 working set > L3 -> FETCH +50%.
template<bool A_BF16, bool DO_GELU, bool OUT_BF16>
__global__ __launch_bounds__(NT)
void ffn_gemm(const void* __restrict__ Ain, const float* __restrict__ Bw,
              const float* __restrict__ bias, void* __restrict__ Out,
              const int* __restrict__ counts, int E, int T, int N, int K)
{
  int mt = blockIdx.y;
  int row0 = 0, cnt = 0, e = 0;
  for (; e < E; ++e) {
    cnt = counts[e];
    int ntl = (cnt + BM - 1) / BM;
    if (mt < ntl) break;
    mt -= ntl; row0 += cnt;
  }
  if (e >= E) return;
  int valid = cnt - mt * BM; if (valid > BM) valid = BM;
  row0 += mt * BM;
  const int n0 = blockIdx.x * BN;

  const float* Be = Bw + (long long)e * N * K;
  const float* be = bias + (long long)e * N;

  __shared__ u16 As[2][BM][BK];
  __shared__ u16 Bs[2][BN][BK];

  const int t = threadIdx.x;
  const int lane = t & 63;
  const int w = t >> 6, wr = w >> 1, wc = w & 1;  // 2x2 waves -> 64x64 each

  f32x4 acc[4][4];
#pragma unroll
  for (int i = 0; i < 4; ++i)
#pragma unroll
    for (int j = 0; j < 4; ++j) acc[i][j] = (f32x4){0.f, 0.f, 0.f, 0.f};

  const int NKT = K / BK;

  // hoisted per-thread global element offsets (K-invariant)
  long long offA[4];
  if constexpr (!A_BF16) {
#pragma unroll
    for (int i = 0; i < 4; ++i) {
      int c = i * NT + t;
      int row = c >> 3, col = (c & 7) << 2;
      int gr = row0 + row; if (gr > T - 1) gr = T - 1;
      offA[i] = (long long)gr * K + col;
    }
  } else {
#pragma unroll
    for (int i = 0; i < 2; ++i) {
      int c = i * NT + t;
      int row = c >> 2, col = (c & 3) << 3;
      int gr = row0 + row; if (gr > T - 1) gr = T - 1;
      offA[i] = (long long)gr * K + col;
    }
  }
  long long offB[4];
#pragma unroll
  for (int i = 0; i < 4; ++i) {
    int c = i * NT + t;
    int row = c >> 3, col = (c & 7) << 2;
    offB[i] = (long long)(n0 + row) * K + col;
  }

  float rA[16]; u16x8 rAu[2]; float rB[16];

  auto load_g = [&](int kt) {
    const int k0 = kt * BK;
    if constexpr (!A_BF16) {
      const float* Af = (const float*)Ain;
#pragma unroll
      for (int i = 0; i < 4; ++i) {
        f32x4 v = *(const f32x4*)(Af + offA[i] + k0);
        rA[i*4+0] = v[0]; rA[i*4+1] = v[1]; rA[i*4+2] = v[2]; rA[i*4+3] = v[3];
      }
    } else {
      const u16* Ab = (const u16*)Ain;
#pragma unroll
      for (int i = 0; i < 2; ++i)
        rAu[i] = *(const u16x8*)(Ab + offA[i] + k0);
    }
#pragma unroll
    for (int i = 0; i < 4; ++i) {
      f32x4 v = *(const f32x4*)(Be + offB[i] + k0);
      rB[i*4+0] = v[0]; rB[i*4+1] = v[1]; rB[i*4+2] = v[2]; rB[i*4+3] = v[3];
    }
  };

  // XOR-swizzle on 16B granules: physical granule = kg ^ ((row>>1)&3)
  auto store_tile = [&](int buf) {
    if constexpr (!A_BF16) {
#pragma unroll
      for (int i = 0; i < 4; ++i) {
        int c = i * NT + t;
        int row = c >> 3, col = (c & 7) << 2;
        int kg = (col >> 3) ^ ((row >> 1) & 3);
        int off = kg * 8 + ((col >> 2) & 1) * 4;
        u16x4 pk = { f2bf(rA[i*4+0]), f2bf(rA[i*4+1]), f2bf(rA[i*4+2]), f2bf(rA[i*4+3]) };
        *(u16x4*)&As[buf][row][off] = pk;
      }
    } else {
#pragma unroll
      for (int i = 0; i < 2; ++i) {
        int c = i * NT + t;
        int row = c >> 2, col = (c & 3) << 3;
        int kg = (col >> 3) ^ ((row >> 1) & 3);
        *(u16x8*)&As[buf][row][kg * 8] = rAu[i];
      }
    }
#pragma unroll
    for (int i = 0; i < 4; ++i) {
      int c = i * NT + t;
      int row = c >> 3, col = (c & 7) << 2;
      int kg = (col >> 3) ^ ((row >> 1) & 3);
      int off = kg * 8 + ((col >> 2) & 1) * 4;
      u16x4 pk = { f2bf(rB[i*4+0]), f2bf(rB[i*4+1]), f2bf(rB[i*4+2]), f2bf(rB[i*4+3]) };
      *(u16x4*)&Bs[buf][row][off] = pk;
    }
  };

  // prologue: LDS buf0 <- tile 0; regs <- tile 1
  load_g(0);
  store_tile(0);
  load_g(1);
  __syncthreads();

  for (int kt = 0; kt < NKT; ++kt) {
    const int cur = kt & 1;

    // fragments for tile kt from LDS
    bf16x8 af[4], bfr[4];
    const int rl = lane & 15;
    const int kg = (lane >> 4) ^ ((rl >> 1) & 3);
#pragma unroll
    for (int mf = 0; mf < 4; ++mf)
      af[mf] = __builtin_bit_cast(bf16x8, *(const u16x8*)&As[cur][wr*64 + mf*16 + rl][kg*8]);
#pragma unroll
    for (int nf = 0; nf < 4; ++nf)
      bfr[nf] = __builtin_bit_cast(bf16x8, *(const u16x8*)&Bs[cur][wc*64 + nf*16 + rl][kg*8]);

    // drain regs (tile kt+1, loaded one full iteration ago) into other buffer
    if (kt + 1 < NKT) store_tile(cur ^ 1);
    // issue loads for tile kt+2 (waited at iter kt+1's store)
    if (kt + 2 < NKT) load_g(kt + 2);

#pragma unroll
    for (int mf = 0; mf < 4; ++mf)
#pragma unroll
      for (int nf = 0; nf < 4; ++nf)
        acc[mf][nf] = __builtin_amdgcn_mfma_f32_16x16x32_bf16(af[mf], bfr[nf], acc[mf][nf], 0, 0, 0);

    if (kt + 1 < NKT) __syncthreads();
  }

  // epilogue: C/D layout col = lane&15, row = (lane>>4)*4 + r  [verified m89/m91]
  const int cl = lane & 15, rg = lane >> 4;
#pragma unroll
  for (int mf = 0; mf < 4; ++mf) {
#pragma unroll
    for (int nf = 0; nf < 4; ++nf) {
      int gcol = n0 + wc*64 + nf*16 + cl;
      float bv = be[gcol];
#pragma unroll
      for (int r = 0; r < 4; ++r) {
        int lrow = wr*64 + mf*16 + rg*4 + r;
        if (lrow < valid) {
          float v = acc[mf][nf][r] + bv;
          if constexpr (DO_GELU)
            v = 0.5f * v * (1.0f + erff(v * 0.70710678118654752f));
          long long idx = (long long)(row0 + lrow) * N + gcol;
          if constexpr (OUT_BF16) ((u16*)Out)[idx] = f2bf(v);
          else                    ((float*)Out)[idx] = v;
        }
      }
    }
  }
}

extern "C" void kernel_launch(void* const* d_in, const int* in_sizes, int n_in,
                              void* d_out, int out_size, void* d_ws, size_t ws_size,
                              hipStream_t stream) {
  const float* inp = (const float*)d_in[0];
  const float* w1  = (const float*)d_in[1];
  const float* b1  = (const float*)d_in[2];
  const float* w2  = (const float*)d_in[3];
  const float* b2  = (const float*)d_in[4];
  const int* cnts  = (const int*)d_in[5];

  const int E = in_sizes[5];
  const int H = in_sizes[2] / E;       // 4096
  const int D = in_sizes[4] / E;       // 1024
  const int T = in_sizes[0] / D;       // 8192

  u16* hbuf = (u16*)d_ws;              // T*H bf16 intermediate (64 MB)

  const int tiles = (T + BM - 1) / BM + E;  // upper bound on sum of per-expert row-tiles
  dim3 blk(NT);

  dim3 g1(H / BN, tiles);
  ffn_gemm<false, true, true><<<g1, blk, 0, stream>>>(
      (const void*)inp, w1, b1, (void*)hbuf, cnts, E, T, H, D);

  dim3 g2(D / BN, tiles);
  ffn_gemm<true, false, false><<<g2, blk, 0, stream>>>(
      (const void*)hbuf, w2, b2, d_out, cnts, E, T, D, H);
}

// Round 4
// 315.342 us; speedup vs baseline: 1.3147x; 1.0426x over previous
//
#include <hip/hip_runtime.h>
#include <hip/hip_bf16.h>

typedef float f32x4 __attribute__((ext_vector_type(4)));
typedef __bf16 bf16x8 __attribute__((ext_vector_type(8)));
typedef unsigned short u16;
typedef unsigned short u16x4 __attribute__((ext_vector_type(4)));
typedef unsigned short u16x8 __attribute__((ext_vector_type(8)));

// fp32 -> bf16 native RNE cvt (compiler emits v_cvt_pk_bf16_f32)
__device__ __forceinline__ u16 f2bf(float f) {
  __bf16 h = (__bf16)f;
  return __builtin_bit_cast(u16, h);
}

// =================== GEMM1: 256x256 tile, BK=32, 8 waves ===================
// Theory (r3 post-mortem): 128^2 tile at K=1024 never amortizes per-step
// overhead (16 MFMA/barrier, 33 FLOP/LDS-byte). 256^2 w/ per-wave 128x64
// doubles both (32 MFMA/barrier-wave, 66 FLOP/LDS-byte); m248 measured
// 848 TF on grouped 256^2 K=1024 (vs our 277).
#define G1_BM 256
#define G1_BN 256
#define G1_BK 32
#define G1_NT 512

__global__ __launch_bounds__(G1_NT, 2)   // cap VGPR at 256 (8 waves = 2/SIMD)
void ffn_gemm1(const float* __restrict__ Af, const float* __restrict__ Bw,
               const float* __restrict__ bias, u16* __restrict__ Out,
               const int* __restrict__ counts, int E, int T, int N, int K)
{
  int mt = blockIdx.y;
  int row0 = 0, cnt = 0, e = 0;
  for (; e < E; ++e) {
    cnt = counts[e];
    int ntl = (cnt + G1_BM - 1) / G1_BM;
    if (mt < ntl) break;
    mt -= ntl; row0 += cnt;
  }
  if (e >= E) return;
  int valid = cnt - mt * G1_BM; if (valid > G1_BM) valid = G1_BM;
  row0 += mt * G1_BM;
  const int n0 = blockIdx.x * G1_BN;
  const float* Be = Bw + (long long)e * N * K;
  const float* be = bias + (long long)e * N;

  // bf16 tiles, 64B rows; XOR-swizzle 16B granule with (row&3):
  // frag-read lanes 0..15 (consecutive rows, same granule) spread over 8
  // banks -> 2-way conflict = free (m136).
  __shared__ u16 As[2][G1_BM * G1_BK];
  __shared__ u16 Bs[2][G1_BN * G1_BK];

  const int t = threadIdx.x;
  const int lane = t & 63;
  const int w = t >> 6, wr = w >> 2, wc = w & 3;  // 2M x 4N waves -> 128x64 each

  f32x4 acc[8][4];
#pragma unroll
  for (int i = 0; i < 8; ++i)
#pragma unroll
    for (int j = 0; j < 4; ++j) acc[i][j] = (f32x4){0.f, 0.f, 0.f, 0.f};

  const int NKT = K / G1_BK;   // 32

  // staging: each thread 4 f32x4 of A and of B (8 threads/row, 16 elems)
  long long offA[4]; int wAo[4];
  long long offB[4]; int wBo[4];
#pragma unroll
  for (int i = 0; i < 4; ++i) {
    int idx = i * G1_NT + t;
    int row = idx >> 3, col4 = idx & 7;          // col = col4*4
    int gr = row0 + row; if (gr > T - 1) gr = T - 1;
    offA[i] = (long long)gr * K + col4 * 4;
    wAo[i] = row * G1_BK + (((col4 >> 1) ^ (row & 3)) << 3) + ((col4 & 1) << 2);
    offB[i] = (long long)(n0 + row) * K + col4 * 4;
    wBo[i] = wAo[i] - ((row0 + row <= T - 1 ? 0 : 0));  // same formula
    wBo[i] = row * G1_BK + (((col4 >> 1) ^ (row & 3)) << 3) + ((col4 & 1) << 2);
  }

  // frag read offsets (elem units), K-invariant
  const int rl = lane & 15, kgr = lane >> 4;
  int aoff[8], boff[4];
#pragma unroll
  for (int mf = 0; mf < 8; ++mf) {
    int row = wr * 128 + mf * 16 + rl;
    aoff[mf] = row * G1_BK + ((kgr ^ (rl & 3)) << 3);
  }
#pragma unroll
  for (int nf = 0; nf < 4; ++nf) {
    int row = wc * 64 + nf * 16 + rl;
    boff[nf] = row * G1_BK + ((kgr ^ (rl & 3)) << 3);
  }

  f32x4 a4[4], b4[4];

  auto load_g = [&](int kt) {
    const int k0 = kt * G1_BK;
#pragma unroll
    for (int i = 0; i < 4; ++i) a4[i] = *(const f32x4*)(Af + offA[i] + k0);
#pragma unroll
    for (int i = 0; i < 4; ++i) b4[i] = *(const f32x4*)(Be + offB[i] + k0);
  };

  auto store_tile = [&](int buf) {
#pragma unroll
    for (int i = 0; i < 4; ++i) {
      u16x4 pa = { f2bf(a4[i][0]), f2bf(a4[i][1]), f2bf(a4[i][2]), f2bf(a4[i][3]) };
      *(u16x4*)&As[buf][wAo[i]] = pa;
    }
#pragma unroll
    for (int i = 0; i < 4; ++i) {
      u16x4 pb = { f2bf(b4[i][0]), f2bf(b4[i][1]), f2bf(b4[i][2]), f2bf(b4[i][3]) };
      *(u16x4*)&Bs[buf][wBo[i]] = pb;
    }
  };

  // prologue: LDS buf0 <- tile0; regs <- tile1 (in flight)
  load_g(0);
  store_tile(0);
  load_g(1);
  __syncthreads();

#pragma unroll 2
  for (int kt = 0; kt < NKT; ++kt) {
    const int cur = kt & 1;

    // all 12 frag reads upfront (lgkm in-order: MFMA waits reads only)
    bf16x8 bfr[4], af[8];
#pragma unroll
    for (int nf = 0; nf < 4; ++nf)
      bfr[nf] = __builtin_bit_cast(bf16x8, *(const u16x8*)&Bs[cur][boff[nf]]);
#pragma unroll
    for (int mf = 0; mf < 8; ++mf)
      af[mf] = __builtin_bit_cast(bf16x8, *(const u16x8*)&As[cur][aoff[mf]]);

    // drain regs (tile kt+1) into other buffer; issue loads for kt+2
    if (kt + 1 < NKT) store_tile(cur ^ 1);
    if (kt + 2 < NKT) load_g(kt + 2);

    __builtin_amdgcn_s_setprio(1);
#pragma unroll
    for (int mf = 0; mf < 8; ++mf)
#pragma unroll
      for (int nf = 0; nf < 4; ++nf)
        acc[mf][nf] = __builtin_amdgcn_mfma_f32_16x16x32_bf16(af[mf], bfr[nf], acc[mf][nf], 0, 0, 0);
    __builtin_amdgcn_s_setprio(0);

    __syncthreads();
  }

  // epilogue: C/D layout col=lane&15, row=(lane>>4)*4+r [m89/m91]
  const int cl = lane & 15, rg = lane >> 4;
#pragma unroll
  for (int nf = 0; nf < 4; ++nf) {
    int gcol = n0 + wc * 64 + nf * 16 + cl;
    float bv = be[gcol];
#pragma unroll
    for (int mf = 0; mf < 8; ++mf) {
#pragma unroll
      for (int r = 0; r < 4; ++r) {
        int lrow = wr * 128 + mf * 16 + rg * 4 + r;
        if (lrow < valid) {
          float v = acc[mf][nf][r] + bv;
          v = 0.5f * v * (1.0f + erff(v * 0.70710678118654752f));
          Out[(long long)(row0 + lrow) * N + gcol] = f2bf(v);
        }
      }
    }
  }
}

// =================== GEMM2: 128x128 tile (round-3 structure, 859 TF) ===================
#define BM 128
#define BN 128
#define BK 32
#define NT 256

template<bool A_BF16, bool DO_GELU, bool OUT_BF16>
__global__ __launch_bounds__(NT)
void ffn_gemm(const void* __restrict__ Ain, const float* __restrict__ Bw,
              const float* __restrict__ bias, void* __restrict__ Out,
              const int* __restrict__ counts, int E, int T, int N, int K)
{
  int mt = blockIdx.y;
  int row0 = 0, cnt = 0, e = 0;
  for (; e < E; ++e) {
    cnt = counts[e];
    int ntl = (cnt + BM - 1) / BM;
    if (mt < ntl) break;
    mt -= ntl; row0 += cnt;
  }
  if (e >= E) return;
  int valid = cnt - mt * BM; if (valid > BM) valid = BM;
  row0 += mt * BM;
  const int n0 = blockIdx.x * BN;

  const float* Be = Bw + (long long)e * N * K;
  const float* be = bias + (long long)e * N;

  __shared__ u16 As[2][BM][BK];
  __shared__ u16 Bs[2][BN][BK];

  const int t = threadIdx.x;
  const int lane = t & 63;
  const int w = t >> 6, wr = w >> 1, wc = w & 1;  // 2x2 waves -> 64x64 each

  f32x4 acc[4][4];
#pragma unroll
  for (int i = 0; i < 4; ++i)
#pragma unroll
    for (int j = 0; j < 4; ++j) acc[i][j] = (f32x4){0.f, 0.f, 0.f, 0.f};

  const int NKT = K / BK;

  long long offA[4];
  if constexpr (!A_BF16) {
#pragma unroll
    for (int i = 0; i < 4; ++i) {
      int c = i * NT + t;
      int row = c >> 3, col = (c & 7) << 2;
      int gr = row0 + row; if (gr > T - 1) gr = T - 1;
      offA[i] = (long long)gr * K + col;
    }
  } else {
#pragma unroll
    for (int i = 0; i < 2; ++i) {
      int c = i * NT + t;
      int row = c >> 2, col = (c & 3) << 3;
      int gr = row0 + row; if (gr > T - 1) gr = T - 1;
      offA[i] = (long long)gr * K + col;
    }
  }
  long long offB[4];
#pragma unroll
  for (int i = 0; i < 4; ++i) {
    int c = i * NT + t;
    int row = c >> 3, col = (c & 7) << 2;
    offB[i] = (long long)(n0 + row) * K + col;
  }

  float rA[16]; u16x8 rAu[2]; float rB[16];

  auto load_g = [&](int kt) {
    const int k0 = kt * BK;
    if constexpr (!A_BF16) {
      const float* Af = (const float*)Ain;
#pragma unroll
      for (int i = 0; i < 4; ++i) {
        f32x4 v = *(const f32x4*)(Af + offA[i] + k0);
        rA[i*4+0] = v[0]; rA[i*4+1] = v[1]; rA[i*4+2] = v[2]; rA[i*4+3] = v[3];
      }
    } else {
      const u16* Ab = (const u16*)Ain;
#pragma unroll
      for (int i = 0; i < 2; ++i)
        rAu[i] = *(const u16x8*)(Ab + offA[i] + k0);
    }
#pragma unroll
    for (int i = 0; i < 4; ++i) {
      f32x4 v = *(const f32x4*)(Be + offB[i] + k0);
      rB[i*4+0] = v[0]; rB[i*4+1] = v[1]; rB[i*4+2] = v[2]; rB[i*4+3] = v[3];
    }
  };

  auto store_tile = [&](int buf) {
    if constexpr (!A_BF16) {
#pragma unroll
      for (int i = 0; i < 4; ++i) {
        int c = i * NT + t;
        int row = c >> 3, col = (c & 7) << 2;
        int kg = (col >> 3) ^ ((row >> 1) & 3);
        int off = kg * 8 + ((col >> 2) & 1) * 4;
        u16x4 pk = { f2bf(rA[i*4+0]), f2bf(rA[i*4+1]), f2bf(rA[i*4+2]), f2bf(rA[i*4+3]) };
        *(u16x4*)&As[buf][row][off] = pk;
      }
    } else {
#pragma unroll
      for (int i = 0; i < 2; ++i) {
        int c = i * NT + t;
        int row = c >> 2, col = (c & 3) << 3;
        int kg = (col >> 3) ^ ((row >> 1) & 3);
        *(u16x8*)&As[buf][row][kg * 8] = rAu[i];
      }
    }
#pragma unroll
    for (int i = 0; i < 4; ++i) {
      int c = i * NT + t;
      int row = c >> 3, col = (c & 7) << 2;
      int kg = (col >> 3) ^ ((row >> 1) & 3);
      int off = kg * 8 + ((col >> 2) & 1) * 4;
      u16x4 pk = { f2bf(rB[i*4+0]), f2bf(rB[i*4+1]), f2bf(rB[i*4+2]), f2bf(rB[i*4+3]) };
      *(u16x4*)&Bs[buf][row][off] = pk;
    }
  };

  load_g(0);
  store_tile(0);
  load_g(1);
  __syncthreads();

  for (int kt = 0; kt < NKT; ++kt) {
    const int cur = kt & 1;

    bf16x8 af[4], bfr[4];
    const int rl = lane & 15;
    const int kg = (lane >> 4) ^ ((rl >> 1) & 3);
#pragma unroll
    for (int mf = 0; mf < 4; ++mf)
      af[mf] = __builtin_bit_cast(bf16x8, *(const u16x8*)&As[cur][wr*64 + mf*16 + rl][kg*8]);
#pragma unroll
    for (int nf = 0; nf < 4; ++nf)
      bfr[nf] = __builtin_bit_cast(bf16x8, *(const u16x8*)&Bs[cur][wc*64 + nf*16 + rl][kg*8]);

    if (kt + 1 < NKT) store_tile(cur ^ 1);
    if (kt + 2 < NKT) load_g(kt + 2);

#pragma unroll
    for (int mf = 0; mf < 4; ++mf)
#pragma unroll
      for (int nf = 0; nf < 4; ++nf)
        acc[mf][nf] = __builtin_amdgcn_mfma_f32_16x16x32_bf16(af[mf], bfr[nf], acc[mf][nf], 0, 0, 0);

    if (kt + 1 < NKT) __syncthreads();
  }

  const int cl = lane & 15, rg = lane >> 4;
#pragma unroll
  for (int mf = 0; mf < 4; ++mf) {
#pragma unroll
    for (int nf = 0; nf < 4; ++nf) {
      int gcol = n0 + wc*64 + nf*16 + cl;
      float bv = be[gcol];
#pragma unroll
      for (int r = 0; r < 4; ++r) {
        int lrow = wr*64 + mf*16 + rg*4 + r;
        if (lrow < valid) {
          float v = acc[mf][nf][r] + bv;
          if constexpr (DO_GELU)
            v = 0.5f * v * (1.0f + erff(v * 0.70710678118654752f));
          long long idx = (long long)(row0 + lrow) * N + gcol;
          if constexpr (OUT_BF16) ((u16*)Out)[idx] = f2bf(v);
          else                    ((float*)Out)[idx] = v;
        }
      }
    }
  }
}

extern "C" void kernel_launch(void* const* d_in, const int* in_sizes, int n_in,
                              void* d_out, int out_size, void* d_ws, size_t ws_size,
                              hipStream_t stream) {
  const float* inp = (const float*)d_in[0];
  const float* w1  = (const float*)d_in[1];
  const float* b1  = (const float*)d_in[2];
  const float* w2  = (const float*)d_in[3];
  const float* b2  = (const float*)d_in[4];
  const int* cnts  = (const int*)d_in[5];

  const int E = in_sizes[5];
  const int H = in_sizes[2] / E;       // 4096
  const int D = in_sizes[4] / E;       // 1024
  const int T = in_sizes[0] / D;       // 8192

  u16* hbuf = (u16*)d_ws;              // T*H bf16 intermediate (64 MB)

  // GEMM1: 256^2 tile
  const int tiles1 = (T + G1_BM - 1) / G1_BM + E;
  dim3 g1(H / G1_BN, tiles1);
  ffn_gemm1<<<g1, dim3(G1_NT), 0, stream>>>(inp, w1, b1, hbuf, cnts, E, T, H, D);

  // GEMM2: 128^2 tile (round-3 structure)
  const int tiles2 = (T + BM - 1) / BM + E;
  dim3 g2(D / BN, tiles2);
  ffn_gemm<true, false, false><<<g2, dim3(NT), 0, stream>>>(
      (const void*)hbuf, w2, b2, d_out, cnts, E, T, D, H);
}